// Round 7
// baseline (263.198 us; speedup 1.0000x reference)
//
#include <hip/hip_runtime.h>
#include <hip/hip_bf16.h>
#include <stdint.h>

#define B_ 1024
#define N_ 128
#define D_ 128
#define H_ 256
#define L_ 64
#define INF_ 0x3FFFFFFF

typedef __attribute__((ext_vector_type(8))) short bf16x8;
typedef __attribute__((ext_vector_type(4))) float f32x4;
typedef __attribute__((ext_vector_type(4))) uint32_t u32x4;
typedef __attribute__((ext_vector_type(2))) uint32_t u32x2;

__device__ __forceinline__ uint32_t pack2(float a, float b) {
    __hip_bfloat162 h = __float22bfloat162_rn(make_float2(a, b));
    uint32_t u;
    __builtin_memcpy(&u, &h, 4);
    return u;
}

// ---------------- weight prep: fragment-linear bf16 layouts in ws ----------------
__global__ void prep_weights(const float* __restrict__ W1, const float* __restrict__ W2,
                             uint16_t* __restrict__ ws) {
    int t = blockIdx.x * 256 + threadIdx.x;
    if (t < 4096) {                       // W1T A-frags: A[m=h][k=f]
        int lane = t & 63, fkb = t >> 6;
        int tm = fkb >> 2, kb = fkb & 3;
        int h  = tm * 16 + (lane & 15);
        int k0 = kb * 32 + (lane >> 4) * 8;
        u32x4 w;
        #pragma unroll
        for (int p = 0; p < 4; ++p)
            w[p] = pack2(W1[(k0 + 2*p) * H_ + h], W1[(k0 + 2*p + 1) * H_ + h]);
        *reinterpret_cast<u32x4*>(&ws[t * 8]) = w;
    } else if (t < 12288) {               // W2 B-frags: B[k][n]
        int t2 = t - 4096;
        int lane = t2 & 63, g = t2 >> 6;
        int tn = g >> 3, kb = g & 7;
        int n  = tn * 16 + (lane & 15);
        int k0 = kb * 32 + (lane >> 4) * 8;
        u32x4 w;
        #pragma unroll
        for (int p = 0; p < 4; ++p)
            w[p] = pack2(W2[(k0 + 2*p) * H_ + n], W2[(k0 + 2*p + 1) * H_ + n]);
        *reinterpret_cast<u32x4*>(&ws[32768 + t2 * 8]) = w;
    }
}

// ---------------- fused kernel: 1 block per graph, 256 threads, 3 blocks/CU ----------------
__global__ __launch_bounds__(256, 3) void fused_kernel(
    const float* __restrict__ x, const float* __restrict__ adj,
    const uint16_t* __restrict__ ws,
    const float* __restrict__ b1g, const float* __restrict__ b2g,
    const float* __restrict__ Wmu, const float* __restrict__ bmu,
    const float* __restrict__ Wlv, const float* __restrict__ blv,
    float* __restrict__ out)
{
    // xabuf 32 KB: BFS-state overlay -> xa frags -> M2 half-buffers
    // rb    16 KB: x f32 chunk (swizzled) -> h1 quarters -> s_g + head partials
    __shared__ __align__(16) uint16_t xabuf[16384];
    __shared__ __align__(16) uint8_t  rb[16384];
    __shared__ __align__(16) uint32_t tnbr[128][4];
    __shared__ float    s_inv[128];
    __shared__ float    s_wm[128];
    __shared__ uint32_t visw[4], actw[4], newlyw[4];
    __shared__ int      s_root;

    uint32_t* adjm     = reinterpret_cast<uint32_t*>(xabuf);        // [512]
    int*      s_order  = reinterpret_cast<int*>(xabuf) + 512;       // [128]
    int*      s_parent = reinterpret_cast<int*>(xabuf) + 640;       // [128]
    int*      s_key    = reinterpret_cast<int*>(xabuf) + 768;       // [128]

    const int tid  = threadIdx.x;
    const int b    = blockIdx.x;
    const int wid  = tid >> 6;          // 0..3
    const int lane = tid & 63;
    const int l15  = lane & 15;
    const int q    = lane >> 4;

    const float4* xg4 = reinterpret_cast<const float4*>(x + (size_t)b * N_ * D_);
    const float*  ag  = adj + (size_t)b * N_ * N_;

    // ---------- prefetch x chunk 0: 1024 float4 / 256 thr = 4 each ----------
    const int prow = tid >> 3;               // base row (i adds 32)
    const int pcol = tid & 7;
    const int pswz = pcol ^ (prow & 7);      // same swizzle for all i (32 ≡ 0 mod 8)
    float4 pf[4];
    #pragma unroll
    for (int i = 0; i < 4; ++i)
        pf[i] = xg4[(prow + i * 32) * 32 + pcol];

    // ---------- init + adj -> bitmasks (2 threads/row) ----------
    if (tid < 128) { s_order[tid] = INF_; s_parent[tid] = 0; }
    if (tid < 4)   { visw[tid] = 0u; actw[tid] = 0u; }
    if (tid == 0)  { s_root = 128; }
    {
        const int v = tid >> 1, hf = tid & 1;
        const float4* ag4 = reinterpret_cast<const float4*>(ag + v * N_ + hf * 64);
        uint32_t w0 = 0, w1 = 0;
        #pragma unroll
        for (int i = 0; i < 16; ++i) {
            float4 f = ag4[i];
            uint32_t bs = (f.x > 0.5f ? 1u : 0u) | (f.y > 0.5f ? 2u : 0u) |
                          (f.z > 0.5f ? 4u : 0u) | (f.w > 0.5f ? 8u : 0u);
            int base = i * 4;
            if (base < 32) w0 |= bs << base; else w1 |= bs << (base - 32);
        }
        adjm[v * 4 + hf * 2]     = w0;
        adjm[v * 4 + hf * 2 + 1] = w1;
    }
    __syncthreads();

    // ---------- active nodes + root ----------
    if (tid < 128) {
        uint32_t any = adjm[tid*4+0] | adjm[tid*4+1] | adjm[tid*4+2] | adjm[tid*4+3];
        if (any) {
            atomicMin(&s_root, tid);
            atomicOr(&actw[tid >> 5], 1u << (tid & 31));
        }
    }
    __syncthreads();
    int counter = 0;
    if (s_root < 128) {
        counter = 1;
        if (tid == 0) {
            s_order[s_root] = 0;
            visw[s_root >> 5] = 1u << (s_root & 31);
        }
    }
    __syncthreads();

    // ---------- level-synchronous FIFO BFS ----------
    for (int step = 0; step < N_ - 1; ++step) {
        if (tid < 4) newlyw[tid] = 0u;
        __syncthreads();
        int newly = 0, po = INF_, par = 0;
        if (tid < 128 && s_order[tid] >= INF_) {
            #pragma unroll
            for (int w = 0; w < 4; ++w) {
                uint32_t m = adjm[tid * 4 + w] & visw[w];
                while (m) {
                    int u = (w << 5) + __ffs(m) - 1; m &= m - 1;
                    int o = s_order[u];
                    if (o < po) { po = o; par = u; }
                }
            }
            newly = (po < INF_);
            if (newly) {
                s_key[tid] = po * N_ + tid;
                atomicOr(&newlyw[tid >> 5], 1u << (tid & 31));
            }
        }
        __syncthreads();
        int myk = newly ? po * N_ + tid : 0x7FFFFFFF;
        int cnt = 0, rank = 0;
        #pragma unroll
        for (int w = 0; w < 4; ++w) {
            uint32_t m = newlyw[w];
            cnt += __popc(m);
            while (m) {
                int u = (w << 5) + __ffs(m) - 1; m &= m - 1;
                rank += (s_key[u] < myk);
            }
        }
        if (newly) {
            s_order[tid]  = counter + rank;
            s_parent[tid] = par;
            atomicOr(&visw[tid >> 5], 1u << (tid & 31));
        }
        counter += cnt;
        __syncthreads();
        if (cnt == 0) break;
    }

    // ---------- tree masks + degrees + pool weights ----------
    if (tid < 128) { tnbr[tid][0] = 0; tnbr[tid][1] = 0; tnbr[tid][2] = 0; tnbr[tid][3] = 0; }
    __syncthreads();
    if (tid < 128 && s_order[tid] > 0 && s_order[tid] < INF_) {
        int p = s_parent[tid];
        atomicOr(&tnbr[tid][p >> 5], 1u << (p & 31));
        atomicOr(&tnbr[p][tid >> 5], 1u << (tid & 31));
    }
    __syncthreads();
    if (tid < 128) {
        int d = 1 + __popc(tnbr[tid][0]) + __popc(tnbr[tid][1]) +
                    __popc(tnbr[tid][2]) + __popc(tnbr[tid][3]);
        int num = __popc(actw[0]) + __popc(actw[1]) + __popc(actw[2]) + __popc(actw[3]);
        int act = (actw[tid >> 5] >> (tid & 31)) & 1;
        s_inv[tid] = 1.0f / (float)d;
        s_wm[tid]  = act ? (1.0f / (float)(num > 0 ? num : 1)) : 0.0f;
    }
    __syncthreads();   // BFS overlay in xabuf dead; agg1 may overwrite

    // ---------- agg1: 4 rounds {stage f32 chunk -> gather -> xa frags} ----------
    float4* rbF4 = reinterpret_cast<float4*>(rb);
    const int gv = tid >> 1, gp2 = tid & 1;     // row, 16-feat half

    for (int r = 0; r < 4; ++r) {
        #pragma unroll
        for (int i = 0; i < 4; ++i)
            rbF4[(prow + i * 32) * 8 + pswz] = pf[i];
        if (r < 3) {                             // prefetch next chunk early (T14)
            #pragma unroll
            for (int i = 0; i < 4; ++i)
                pf[i] = xg4[(prow + i * 32) * 32 + (r + 1) * 8 + pcol];
        }
        __syncthreads();
        float acc[16];
        #pragma unroll
        for (int k = 0; k < 4; ++k) {
            float4 a = rbF4[gv * 8 + ((gp2 * 4 + k) ^ (gv & 7))];
            acc[k*4+0] = a.x; acc[k*4+1] = a.y; acc[k*4+2] = a.z; acc[k*4+3] = a.w;
        }
        #pragma unroll
        for (int w = 0; w < 4; ++w) {
            uint32_t m = tnbr[gv][w];
            while (m) {
                int u = (w << 5) + __ffs(m) - 1; m &= m - 1;
                #pragma unroll
                for (int k = 0; k < 4; ++k) {
                    float4 n = rbF4[u * 8 + ((gp2 * 4 + k) ^ (u & 7))];
                    acc[k*4+0] += n.x; acc[k*4+1] += n.y;
                    acc[k*4+2] += n.z; acc[k*4+3] += n.w;
                }
            }
        }
        const float inv = s_inv[gv];
        #pragma unroll
        for (int gg = 0; gg < 2; ++gg) {
            const int gp = gp2 * 2 + gg;
            u32x4 wv;
            wv[0] = pack2(acc[gg*8+0] * inv, acc[gg*8+1] * inv);
            wv[1] = pack2(acc[gg*8+2] * inv, acc[gg*8+3] * inv);
            wv[2] = pack2(acc[gg*8+4] * inv, acc[gg*8+5] * inv);
            wv[3] = pack2(acc[gg*8+6] * inv, acc[gg*8+7] * inv);
            *reinterpret_cast<u32x4*>(
                &xabuf[(((gv >> 4) * 4 + r) * 64 + gp * 16 + (gv & 15)) * 8]) = wv;
        }
        __syncthreads();
    }

    // ---------- m1/m2 interleaved over 4 h-chunks (64 h each), acc2 persistent ----------
    uint16_t* h1 = reinterpret_cast<uint16_t*>(rb);
    const bf16x8* wsA = reinterpret_cast<const bf16x8*>(ws);
    const bf16x8* wsB = reinterpret_cast<const bf16x8*>(ws + 32768);

    f32x4 acc2[8][4];          // wave owns n-tiles wid*4..+3, all 8 node-tiles (128 acc regs)
    #pragma unroll
    for (int t = 0; t < 8; ++t)
        #pragma unroll
        for (int j = 0; j < 4; ++j) acc2[t][j] = (f32x4){0.f, 0.f, 0.f, 0.f};

    const int kbl_w = wid >> 1;                                 // 32-h half within chunk
    const int sl    = l15 + 16 * (((wid & 1) * 2 + (q >> 1)) & 3);

    for (int hc = 0; hc < 4; ++hc) {
        const int tm = hc * 4 + wid;                            // h-tile (m1 A index)
        const int m0 = tm * 16 + q * 4;
        // group 0 (node-tiles 0..3): compute -> barrier -> write
        f32x4 acc1[4];
        #pragma unroll
        for (int j = 0; j < 4; ++j) acc1[j] = (f32x4){0.f, 0.f, 0.f, 0.f};
        #pragma unroll
        for (int kb = 0; kb < 4; ++kb) {
            bf16x8 afr = wsA[(tm * 4 + kb) * 64 + lane];
            #pragma unroll
            for (int j = 0; j < 4; ++j) {
                bf16x8 bfr = *reinterpret_cast<const bf16x8*>(
                    &xabuf[((j * 4 + kb) * 64 + lane) * 8]);
                acc1[j] = __builtin_amdgcn_mfma_f32_16x16x32_bf16(
                    afr, bfr, acc1[j], 0, 0, 0);
            }
        }
        __syncthreads();   // prev m2 finished reading h1q
        {
            f32x4 bb = *reinterpret_cast<const f32x4*>(b1g + m0);
            #pragma unroll
            for (int j = 0; j < 4; ++j) {
                f32x4 v = acc1[j];
                float v0 = fmaxf(v[0] + bb[0], 0.f), v1 = fmaxf(v[1] + bb[1], 0.f);
                float v2 = fmaxf(v[2] + bb[2], 0.f), v3 = fmaxf(v[3] + bb[3], 0.f);
                u32x2 w; w[0] = pack2(v0, v1); w[1] = pack2(v2, v3);
                *reinterpret_cast<u32x2*>(
                    &h1[((j * 2 + kbl_w) * 64 + sl) * 8 + (q & 1) * 4]) = w;
            }
        }
        // group 1 (node-tiles 4..7): compute -> write (no barrier needed before write)
        #pragma unroll
        for (int j = 0; j < 4; ++j) acc1[j] = (f32x4){0.f, 0.f, 0.f, 0.f};
        #pragma unroll
        for (int kb = 0; kb < 4; ++kb) {
            bf16x8 afr = wsA[(tm * 4 + kb) * 64 + lane];
            #pragma unroll
            for (int j = 0; j < 4; ++j) {
                bf16x8 bfr = *reinterpret_cast<const bf16x8*>(
                    &xabuf[(((4 + j) * 4 + kb) * 64 + lane) * 8]);
                acc1[j] = __builtin_amdgcn_mfma_f32_16x16x32_bf16(
                    afr, bfr, acc1[j], 0, 0, 0);
            }
        }
        {
            f32x4 bb = *reinterpret_cast<const f32x4*>(b1g + m0);
            #pragma unroll
            for (int j = 0; j < 4; ++j) {
                f32x4 v = acc1[j];
                float v0 = fmaxf(v[0] + bb[0], 0.f), v1 = fmaxf(v[1] + bb[1], 0.f);
                float v2 = fmaxf(v[2] + bb[2], 0.f), v3 = fmaxf(v[3] + bb[3], 0.f);
                u32x2 w; w[0] = pack2(v0, v1); w[1] = pack2(v2, v3);
                *reinterpret_cast<u32x2*>(
                    &h1[(((4 + j) * 2 + kbl_w) * 64 + sl) * 8 + (q & 1) * 4]) = w;
            }
        }
        __syncthreads();   // h1q ready
        // m2: accumulate this chunk's k-range into persistent acc2
        #pragma unroll
        for (int kbl = 0; kbl < 2; ++kbl) {
            const int kb2 = hc * 2 + kbl;
            bf16x8 bfr0 = wsB[((wid * 4 + 0) * 8 + kb2) * 64 + lane];
            bf16x8 bfr1 = wsB[((wid * 4 + 1) * 8 + kb2) * 64 + lane];
            bf16x8 bfr2 = wsB[((wid * 4 + 2) * 8 + kb2) * 64 + lane];
            bf16x8 bfr3 = wsB[((wid * 4 + 3) * 8 + kb2) * 64 + lane];
            #pragma unroll
            for (int t = 0; t < 8; ++t) {
                bf16x8 a2 = *reinterpret_cast<const bf16x8*>(
                    &h1[((t * 2 + kbl) * 64 + lane) * 8]);
                acc2[t][0] = __builtin_amdgcn_mfma_f32_16x16x32_bf16(a2, bfr0, acc2[t][0], 0, 0, 0);
                acc2[t][1] = __builtin_amdgcn_mfma_f32_16x16x32_bf16(a2, bfr1, acc2[t][1], 0, 0, 0);
                acc2[t][2] = __builtin_amdgcn_mfma_f32_16x16x32_bf16(a2, bfr2, acc2[t][2], 0, 0, 0);
                acc2[t][3] = __builtin_amdgcn_mfma_f32_16x16x32_bf16(a2, bfr3, acc2[t][3], 0, 0, 0);
            }
        }
    }

    // ---------- agg2 in two h2-halves; each half handled by the 2 waves that own it ----------
    float* sgf = reinterpret_cast<float*>(rb);            // s_g[256] (1 KB)
    #pragma unroll
    for (int hf = 0; hf < 2; ++hf) {
        const int owner = ((wid >> 1) == hf);
        if (owner) {                       // write this half's M2 frags (releases own acc2)
            #pragma unroll
            for (int t = 0; t < 8; ++t) {
                const int kbh = t >> 1;
                const int slw = l15 + 16 * ((2 * t + (q >> 1)) & 3);
                #pragma unroll
                for (int j = 0; j < 4; ++j) {
                    const int tnl = (wid & 1) * 4 + j;
                    f32x4 v = acc2[t][j];
                    u32x2 w; w[0] = pack2(v[0], v[1]); w[1] = pack2(v[2], v[3]);
                    *reinterpret_cast<u32x2*>(
                        &xabuf[((tnl * 4 + kbh) * 64 + slw) * 8 + (q & 1) * 4]) = w;
                }
            }
        }
        __syncthreads();   // M2 half ready (also fences h1 reads at hf=0)
        if (owner) {
            f32x4 acc3[8][4];
            #pragma unroll
            for (int t = 0; t < 8; ++t)
                #pragma unroll
                for (int jj = 0; jj < 4; ++jj) acc3[t][jj] = (f32x4){0.f, 0.f, 0.f, 0.f};
            #pragma unroll
            for (int kb = 0; kb < 4; ++kb) {
                bf16x8 bfr0 = *reinterpret_cast<const bf16x8*>(
                    &xabuf[((((wid & 1) * 4 + 0) * 4 + kb) * 64 + lane) * 8]);
                bf16x8 bfr1 = *reinterpret_cast<const bf16x8*>(
                    &xabuf[((((wid & 1) * 4 + 1) * 4 + kb) * 64 + lane) * 8]);
                bf16x8 bfr2 = *reinterpret_cast<const bf16x8*>(
                    &xabuf[((((wid & 1) * 4 + 2) * 4 + kb) * 64 + lane) * 8]);
                bf16x8 bfr3 = *reinterpret_cast<const bf16x8*>(
                    &xabuf[((((wid & 1) * 4 + 3) * 4 + kb) * 64 + lane) * 8]);
                #pragma unroll
                for (int t = 0; t < 8; ++t) {
                    int v = t * 16 + l15;
                    uint32_t word = tnbr[v][kb];
                    uint32_t by = (word >> (q * 8)) & 0xFFu;
                    if ((v >> 3) == kb * 4 + q) by |= 1u << (v & 7);
                    u32x4 pm;
                    #pragma unroll
                    for (int pp = 0; pp < 4; ++pp)
                        pm[pp] = (((by >> (2 * pp)) & 1u) ? 0x3F80u : 0u) |
                                 (((by >> (2 * pp + 1)) & 1u) ? 0x3F800000u : 0u);
                    bf16x8 a3 = __builtin_bit_cast(bf16x8, pm);
                    acc3[t][0] = __builtin_amdgcn_mfma_f32_16x16x32_bf16(a3, bfr0, acc3[t][0], 0, 0, 0);
                    acc3[t][1] = __builtin_amdgcn_mfma_f32_16x16x32_bf16(a3, bfr1, acc3[t][1], 0, 0, 0);
                    acc3[t][2] = __builtin_amdgcn_mfma_f32_16x16x32_bf16(a3, bfr2, acc3[t][2], 0, 0, 0);
                    acc3[t][3] = __builtin_amdgcn_mfma_f32_16x16x32_bf16(a3, bfr3, acc3[t][3], 0, 0, 0);
                }
            }
            float ps[4] = {0.f, 0.f, 0.f, 0.f};
            #pragma unroll
            for (int t = 0; t < 8; ++t) {
                const int v0 = t * 16 + q * 4;
                f32x4 iv = *reinterpret_cast<const f32x4*>(&s_inv[v0]);
                f32x4 wm = *reinterpret_cast<const f32x4*>(&s_wm[v0]);
                #pragma unroll
                for (int jj = 0; jj < 4; ++jj) {
                    const float bc = b2g[hf * 128 + ((wid & 1) * 4 + jj) * 16 + l15];
                    f32x4 a = acc3[t][jj];
                    #pragma unroll
                    for (int r = 0; r < 4; ++r)
                        ps[jj] += fmaxf(fmaf(a[r], iv[r], bc), 0.f) * wm[r];
                }
            }
            #pragma unroll
            for (int jj = 0; jj < 4; ++jj) {
                ps[jj] += __shfl_xor(ps[jj], 16);
                ps[jj] += __shfl_xor(ps[jj], 32);
                if (q == 0)
                    sgf[hf * 128 + ((wid & 1) * 4 + jj) * 16 + l15] = ps[jj];
            }
        }
        __syncthreads();   // half consumed before next half overwrites xabuf / sgf done
    }

    // ---------- heads inline: out = g @ {Wmu,Wlv} + bias (2 thr / output) ----------
    {
        float* sp = reinterpret_cast<float*>(rb + 1024);   // [2][128] partials
        const int oi = tid & 127, part = tid >> 7;
        const int which = oi >> 6, l = oi & 63;
        const float* W = which ? Wlv : Wmu;
        float acc = 0.f;
        const int c0 = part * 128;
        #pragma unroll 8
        for (int cc = 0; cc < 128; ++cc)
            acc = fmaf(sgf[c0 + cc], W[(c0 + cc) * L_ + l], acc);
        sp[part * 128 + oi] = acc;
        __syncthreads();
        if (tid < 128) {
            const int w2 = tid >> 6, l2 = tid & 63;
            float r = sp[tid] + sp[128 + tid];
            r += w2 ? blv[l2] : bmu[l2];
            out[(size_t)w2 * B_ * L_ + (size_t)b * L_ + l2] = r;
        }
    }
}

extern "C" void kernel_launch(void* const* d_in, const int* in_sizes, int n_in,
                              void* d_out, int out_size, void* d_ws, size_t ws_size,
                              hipStream_t stream) {
    const float* x   = (const float*)d_in[0];
    const float* adj = (const float*)d_in[1];
    const float* W1  = (const float*)d_in[2];
    const float* b1  = (const float*)d_in[3];
    const float* W2  = (const float*)d_in[4];
    const float* b2  = (const float*)d_in[5];
    const float* Wmu = (const float*)d_in[6];
    const float* bmu = (const float*)d_in[7];
    const float* Wlv = (const float*)d_in[8];
    const float* blv = (const float*)d_in[9];
    float* out = (float*)d_out;
    uint16_t* ws = (uint16_t*)d_ws;

    hipLaunchKernelGGL(prep_weights, dim3(48), dim3(256), 0, stream, W1, W2, ws);
    hipLaunchKernelGGL(fused_kernel, dim3(B_), dim3(256), 0, stream,
                       x, adj, ws, b1, b2, Wmu, bmu, Wlv, blv, out);
}

// Round 8
// 157.191 us; speedup vs baseline: 1.6744x; 1.6744x over previous
//
#include <hip/hip_runtime.h>
#include <hip/hip_bf16.h>
#include <stdint.h>

#define B_ 1024
#define N_ 128
#define D_ 128
#define H_ 256
#define L_ 64
#define INF_ 0x3FFFFFFF

typedef __attribute__((ext_vector_type(8))) short bf16x8;
typedef __attribute__((ext_vector_type(4))) float f32x4;
typedef __attribute__((ext_vector_type(4))) uint32_t u32x4;
typedef __attribute__((ext_vector_type(2))) uint32_t u32x2;

__device__ __forceinline__ uint32_t pack2(float a, float b) {
    __hip_bfloat162 h = __float22bfloat162_rn(make_float2(a, b));
    uint32_t u;
    __builtin_memcpy(&u, &h, 4);
    return u;
}

// ---------------- weight prep: fragment-linear bf16 layouts in ws ----------------
__global__ void prep_weights(const float* __restrict__ W1, const float* __restrict__ W2,
                             uint16_t* __restrict__ ws) {
    int t = blockIdx.x * 256 + threadIdx.x;
    if (t < 4096) {                       // W1T A-frags: A[m=h][k=f]
        int lane = t & 63, fkb = t >> 6;
        int tm = fkb >> 2, kb = fkb & 3;
        int h  = tm * 16 + (lane & 15);
        int k0 = kb * 32 + (lane >> 4) * 8;
        u32x4 w;
        #pragma unroll
        for (int p = 0; p < 4; ++p)
            w[p] = pack2(W1[(k0 + 2*p) * H_ + h], W1[(k0 + 2*p + 1) * H_ + h]);
        *reinterpret_cast<u32x4*>(&ws[t * 8]) = w;
    } else if (t < 12288) {               // W2 B-frags: B[k][n]
        int t2 = t - 4096;
        int lane = t2 & 63, g = t2 >> 6;
        int tn = g >> 3, kb = g & 7;
        int n  = tn * 16 + (lane & 15);
        int k0 = kb * 32 + (lane >> 4) * 8;
        u32x4 w;
        #pragma unroll
        for (int p = 0; p < 4; ++p)
            w[p] = pack2(W2[(k0 + 2*p) * H_ + n], W2[(k0 + 2*p + 1) * H_ + n]);
        *reinterpret_cast<u32x4*>(&ws[32768 + t2 * 8]) = w;
    }
}

// ---------------- fused kernel: 1 block per graph, 256 threads, 3 blocks/CU ----------------
__global__ __launch_bounds__(256, 3) void fused_kernel(
    const float* __restrict__ x, const float* __restrict__ adj,
    const uint16_t* __restrict__ ws,
    const float* __restrict__ b1g, const float* __restrict__ b2g,
    const float* __restrict__ Wmu, const float* __restrict__ bmu,
    const float* __restrict__ Wlv, const float* __restrict__ blv,
    float* __restrict__ out)
{
    // xabuf 32 KB: BFS-state overlay -> xa frags -> M2 half-buffers
    // rb    16 KB: x f32 chunk (swizzled) -> h1 quarters -> s_g + head partials
    __shared__ __align__(16) uint16_t xabuf[16384];
    __shared__ __align__(16) uint8_t  rb[16384];
    __shared__ __align__(16) uint32_t tnbr[128][4];
    __shared__ float    s_inv[128];
    __shared__ float    s_wm[128];
    __shared__ uint32_t visw[4], actw[4], newlyw[4];
    __shared__ int      s_root;

    uint32_t* adjm     = reinterpret_cast<uint32_t*>(xabuf);        // [512]
    int*      s_order  = reinterpret_cast<int*>(xabuf) + 512;       // [128]
    int*      s_parent = reinterpret_cast<int*>(xabuf) + 640;       // [128]
    int*      s_key    = reinterpret_cast<int*>(xabuf) + 768;       // [128]

    const int tid  = threadIdx.x;
    const int b    = blockIdx.x;
    const int wid  = tid >> 6;          // 0..3
    const int lane = tid & 63;
    const int l15  = lane & 15;
    const int q    = lane >> 4;

    const float4* xg4 = reinterpret_cast<const float4*>(x + (size_t)b * N_ * D_);
    const float*  ag  = adj + (size_t)b * N_ * N_;

    // ---------- prefetch x chunk 0: 1024 float4 / 256 thr = 4 each ----------
    const int prow = tid >> 3;               // base row (i adds 32)
    const int pcol = tid & 7;
    const int pswz = pcol ^ (prow & 7);      // same swizzle for all i (32 ≡ 0 mod 8)
    float4 pf[4];
    #pragma unroll
    for (int i = 0; i < 4; ++i)
        pf[i] = xg4[(prow + i * 32) * 32 + pcol];

    // ---------- init + adj -> bitmasks (2 threads/row) ----------
    if (tid < 128) { s_order[tid] = INF_; s_parent[tid] = 0; }
    if (tid < 4)   { visw[tid] = 0u; actw[tid] = 0u; }
    if (tid == 0)  { s_root = 128; }
    {
        const int v = tid >> 1, hf = tid & 1;
        const float4* ag4 = reinterpret_cast<const float4*>(ag + v * N_ + hf * 64);
        uint32_t w0 = 0, w1 = 0;
        #pragma unroll
        for (int i = 0; i < 16; ++i) {
            float4 f = ag4[i];
            uint32_t bs = (f.x > 0.5f ? 1u : 0u) | (f.y > 0.5f ? 2u : 0u) |
                          (f.z > 0.5f ? 4u : 0u) | (f.w > 0.5f ? 8u : 0u);
            int base = i * 4;
            if (base < 32) w0 |= bs << base; else w1 |= bs << (base - 32);
        }
        adjm[v * 4 + hf * 2]     = w0;
        adjm[v * 4 + hf * 2 + 1] = w1;
    }
    __syncthreads();

    // ---------- active nodes + root ----------
    if (tid < 128) {
        uint32_t any = adjm[tid*4+0] | adjm[tid*4+1] | adjm[tid*4+2] | adjm[tid*4+3];
        if (any) {
            atomicMin(&s_root, tid);
            atomicOr(&actw[tid >> 5], 1u << (tid & 31));
        }
    }
    __syncthreads();
    int counter = 0;
    if (s_root < 128) {
        counter = 1;
        if (tid == 0) {
            s_order[s_root] = 0;
            visw[s_root >> 5] = 1u << (s_root & 31);
        }
    }
    __syncthreads();

    // ---------- level-synchronous FIFO BFS ----------
    for (int step = 0; step < N_ - 1; ++step) {
        if (tid < 4) newlyw[tid] = 0u;
        __syncthreads();
        int newly = 0, po = INF_, par = 0;
        if (tid < 128 && s_order[tid] >= INF_) {
            #pragma unroll
            for (int w = 0; w < 4; ++w) {
                uint32_t m = adjm[tid * 4 + w] & visw[w];
                while (m) {
                    int u = (w << 5) + __ffs(m) - 1; m &= m - 1;
                    int o = s_order[u];
                    if (o < po) { po = o; par = u; }
                }
            }
            newly = (po < INF_);
            if (newly) {
                s_key[tid] = po * N_ + tid;
                atomicOr(&newlyw[tid >> 5], 1u << (tid & 31));
            }
        }
        __syncthreads();
        int myk = newly ? po * N_ + tid : 0x7FFFFFFF;
        int cnt = 0, rank = 0;
        #pragma unroll
        for (int w = 0; w < 4; ++w) {
            uint32_t m = newlyw[w];
            cnt += __popc(m);
            while (m) {
                int u = (w << 5) + __ffs(m) - 1; m &= m - 1;
                rank += (s_key[u] < myk);
            }
        }
        if (newly) {
            s_order[tid]  = counter + rank;
            s_parent[tid] = par;
            atomicOr(&visw[tid >> 5], 1u << (tid & 31));
        }
        counter += cnt;
        __syncthreads();
        if (cnt == 0) break;
    }

    // ---------- tree masks + degrees + pool weights ----------
    if (tid < 128) { tnbr[tid][0] = 0; tnbr[tid][1] = 0; tnbr[tid][2] = 0; tnbr[tid][3] = 0; }
    __syncthreads();
    if (tid < 128 && s_order[tid] > 0 && s_order[tid] < INF_) {
        int p = s_parent[tid];
        atomicOr(&tnbr[tid][p >> 5], 1u << (p & 31));
        atomicOr(&tnbr[p][tid >> 5], 1u << (tid & 31));
    }
    __syncthreads();
    if (tid < 128) {
        int d = 1 + __popc(tnbr[tid][0]) + __popc(tnbr[tid][1]) +
                    __popc(tnbr[tid][2]) + __popc(tnbr[tid][3]);
        int num = __popc(actw[0]) + __popc(actw[1]) + __popc(actw[2]) + __popc(actw[3]);
        int act = (actw[tid >> 5] >> (tid & 31)) & 1;
        s_inv[tid] = 1.0f / (float)d;
        s_wm[tid]  = act ? (1.0f / (float)(num > 0 ? num : 1)) : 0.0f;
    }
    __syncthreads();   // BFS overlay in xabuf dead; agg1 may overwrite

    // ---------- agg1: 4 rounds {stage f32 chunk -> gather -> xa frags} ----------
    float4* rbF4 = reinterpret_cast<float4*>(rb);
    const int gv = tid >> 1, gp2 = tid & 1;     // row, 16-feat half

    for (int r = 0; r < 4; ++r) {
        #pragma unroll
        for (int i = 0; i < 4; ++i)
            rbF4[(prow + i * 32) * 8 + pswz] = pf[i];
        if (r < 3) {                             // prefetch next chunk early (T14)
            #pragma unroll
            for (int i = 0; i < 4; ++i)
                pf[i] = xg4[(prow + i * 32) * 32 + (r + 1) * 8 + pcol];
        }
        __syncthreads();
        float acc[16];
        #pragma unroll
        for (int k = 0; k < 4; ++k) {
            float4 a = rbF4[gv * 8 + ((gp2 * 4 + k) ^ (gv & 7))];
            acc[k*4+0] = a.x; acc[k*4+1] = a.y; acc[k*4+2] = a.z; acc[k*4+3] = a.w;
        }
        #pragma unroll
        for (int w = 0; w < 4; ++w) {
            uint32_t m = tnbr[gv][w];
            while (m) {
                int u = (w << 5) + __ffs(m) - 1; m &= m - 1;
                #pragma unroll
                for (int k = 0; k < 4; ++k) {
                    float4 n = rbF4[u * 8 + ((gp2 * 4 + k) ^ (u & 7))];
                    acc[k*4+0] += n.x; acc[k*4+1] += n.y;
                    acc[k*4+2] += n.z; acc[k*4+3] += n.w;
                }
            }
        }
        const float inv = s_inv[gv];
        #pragma unroll
        for (int gg = 0; gg < 2; ++gg) {
            const int gp = gp2 * 2 + gg;
            u32x4 wv;
            wv[0] = pack2(acc[gg*8+0] * inv, acc[gg*8+1] * inv);
            wv[1] = pack2(acc[gg*8+2] * inv, acc[gg*8+3] * inv);
            wv[2] = pack2(acc[gg*8+4] * inv, acc[gg*8+5] * inv);
            wv[3] = pack2(acc[gg*8+6] * inv, acc[gg*8+7] * inv);
            *reinterpret_cast<u32x4*>(
                &xabuf[(((gv >> 4) * 4 + r) * 64 + gp * 16 + (gv & 15)) * 8]) = wv;
        }
        __syncthreads();
    }

    // ---------- m1/m2 interleaved over 4 h-chunks (64 h each), acc2 persistent ----------
    // m2 n-tile ownership INTERLEAVED: acc2[t][j] <-> global tn = j*4+wid.
    uint16_t* h1 = reinterpret_cast<uint16_t*>(rb);
    const bf16x8* wsA = reinterpret_cast<const bf16x8*>(ws);
    const bf16x8* wsB = reinterpret_cast<const bf16x8*>(ws + 32768);

    f32x4 acc2[8][4];
    #pragma unroll
    for (int t = 0; t < 8; ++t)
        #pragma unroll
        for (int j = 0; j < 4; ++j) acc2[t][j] = (f32x4){0.f, 0.f, 0.f, 0.f};

    const int kbl_w = wid >> 1;                                 // 32-h half within chunk
    const int sl    = l15 + 16 * (((wid & 1) * 2 + (q >> 1)) & 3);

    for (int hc = 0; hc < 4; ++hc) {
        const int tm = hc * 4 + wid;                            // h-tile (m1 A index)
        const int m0 = tm * 16 + q * 4;
        // group 0 (node-tiles 0..3): compute -> barrier -> write
        f32x4 acc1[4];
        #pragma unroll
        for (int j = 0; j < 4; ++j) acc1[j] = (f32x4){0.f, 0.f, 0.f, 0.f};
        #pragma unroll
        for (int kb = 0; kb < 4; ++kb) {
            bf16x8 afr = wsA[(tm * 4 + kb) * 64 + lane];
            #pragma unroll
            for (int j = 0; j < 4; ++j) {
                bf16x8 bfr = *reinterpret_cast<const bf16x8*>(
                    &xabuf[((j * 4 + kb) * 64 + lane) * 8]);
                acc1[j] = __builtin_amdgcn_mfma_f32_16x16x32_bf16(
                    afr, bfr, acc1[j], 0, 0, 0);
            }
        }
        __syncthreads();   // prev m2 finished reading h1q
        {
            f32x4 bb = *reinterpret_cast<const f32x4*>(b1g + m0);
            #pragma unroll
            for (int j = 0; j < 4; ++j) {
                f32x4 v = acc1[j];
                float v0 = fmaxf(v[0] + bb[0], 0.f), v1 = fmaxf(v[1] + bb[1], 0.f);
                float v2 = fmaxf(v[2] + bb[2], 0.f), v3 = fmaxf(v[3] + bb[3], 0.f);
                u32x2 w; w[0] = pack2(v0, v1); w[1] = pack2(v2, v3);
                *reinterpret_cast<u32x2*>(
                    &h1[((j * 2 + kbl_w) * 64 + sl) * 8 + (q & 1) * 4]) = w;
            }
        }
        // group 1 (node-tiles 4..7): compute -> write
        #pragma unroll
        for (int j = 0; j < 4; ++j) acc1[j] = (f32x4){0.f, 0.f, 0.f, 0.f};
        #pragma unroll
        for (int kb = 0; kb < 4; ++kb) {
            bf16x8 afr = wsA[(tm * 4 + kb) * 64 + lane];
            #pragma unroll
            for (int j = 0; j < 4; ++j) {
                bf16x8 bfr = *reinterpret_cast<const bf16x8*>(
                    &xabuf[(((4 + j) * 4 + kb) * 64 + lane) * 8]);
                acc1[j] = __builtin_amdgcn_mfma_f32_16x16x32_bf16(
                    afr, bfr, acc1[j], 0, 0, 0);
            }
        }
        {
            f32x4 bb = *reinterpret_cast<const f32x4*>(b1g + m0);
            #pragma unroll
            for (int j = 0; j < 4; ++j) {
                f32x4 v = acc1[j];
                float v0 = fmaxf(v[0] + bb[0], 0.f), v1 = fmaxf(v[1] + bb[1], 0.f);
                float v2 = fmaxf(v[2] + bb[2], 0.f), v3 = fmaxf(v[3] + bb[3], 0.f);
                u32x2 w; w[0] = pack2(v0, v1); w[1] = pack2(v2, v3);
                *reinterpret_cast<u32x2*>(
                    &h1[(((4 + j) * 2 + kbl_w) * 64 + sl) * 8 + (q & 1) * 4]) = w;
            }
        }
        __syncthreads();   // h1q ready
        // m2: accumulate this chunk's k-range into persistent acc2 (tn = j*4+wid)
        #pragma unroll
        for (int kbl = 0; kbl < 2; ++kbl) {
            const int kb2 = hc * 2 + kbl;
            bf16x8 bfr0 = wsB[((0 * 4 + wid) * 8 + kb2) * 64 + lane];
            bf16x8 bfr1 = wsB[((1 * 4 + wid) * 8 + kb2) * 64 + lane];
            bf16x8 bfr2 = wsB[((2 * 4 + wid) * 8 + kb2) * 64 + lane];
            bf16x8 bfr3 = wsB[((3 * 4 + wid) * 8 + kb2) * 64 + lane];
            #pragma unroll
            for (int t = 0; t < 8; ++t) {
                bf16x8 a2 = *reinterpret_cast<const bf16x8*>(
                    &h1[((t * 2 + kbl) * 64 + lane) * 8]);
                acc2[t][0] = __builtin_amdgcn_mfma_f32_16x16x32_bf16(a2, bfr0, acc2[t][0], 0, 0, 0);
                acc2[t][1] = __builtin_amdgcn_mfma_f32_16x16x32_bf16(a2, bfr1, acc2[t][1], 0, 0, 0);
                acc2[t][2] = __builtin_amdgcn_mfma_f32_16x16x32_bf16(a2, bfr2, acc2[t][2], 0, 0, 0);
                acc2[t][3] = __builtin_amdgcn_mfma_f32_16x16x32_bf16(a2, bfr3, acc2[t][3], 0, 0, 0);
            }
        }
    }

    // ---------- agg2 in two h2-halves; ALL waves write + compute each half ----------
    float* sgf = reinterpret_cast<float*>(rb);            // s_g[256] (1 KB)
    #pragma unroll
    for (int hf = 0; hf < 2; ++hf) {
        // write this half's M2 frags: j = hf*2+jj, local tile tnl = jj*4+wid (0..7)
        #pragma unroll
        for (int t = 0; t < 8; ++t) {
            const int kbh = t >> 1;
            const int slw = l15 + 16 * ((2 * t + (q >> 1)) & 3);
            #pragma unroll
            for (int jj = 0; jj < 2; ++jj) {
                const int tnl = jj * 4 + wid;
                f32x4 v = acc2[t][hf * 2 + jj];
                u32x2 w; w[0] = pack2(v[0], v[1]); w[1] = pack2(v[2], v[3]);
                *reinterpret_cast<u32x2*>(
                    &xabuf[((tnl * 4 + kbh) * 64 + slw) * 8 + (q & 1) * 4]) = w;
            }
        }
        __syncthreads();   // M2 half ready (also fences h1 reads at hf=0)
        {
            f32x4 acc3[8][2];
            #pragma unroll
            for (int t = 0; t < 8; ++t) {
                acc3[t][0] = (f32x4){0.f, 0.f, 0.f, 0.f};
                acc3[t][1] = (f32x4){0.f, 0.f, 0.f, 0.f};
            }
            #pragma unroll
            for (int kb = 0; kb < 4; ++kb) {
                bf16x8 bfr0 = *reinterpret_cast<const bf16x8*>(
                    &xabuf[(((0 * 4 + wid) * 4 + kb) * 64 + lane) * 8]);
                bf16x8 bfr1 = *reinterpret_cast<const bf16x8*>(
                    &xabuf[(((1 * 4 + wid) * 4 + kb) * 64 + lane) * 8]);
                #pragma unroll
                for (int t = 0; t < 8; ++t) {
                    int v = t * 16 + l15;
                    uint32_t word = tnbr[v][kb];
                    uint32_t by = (word >> (q * 8)) & 0xFFu;
                    if ((v >> 3) == kb * 4 + q) by |= 1u << (v & 7);
                    u32x4 pm;
                    #pragma unroll
                    for (int pp = 0; pp < 4; ++pp)
                        pm[pp] = (((by >> (2 * pp)) & 1u) ? 0x3F80u : 0u) |
                                 (((by >> (2 * pp + 1)) & 1u) ? 0x3F800000u : 0u);
                    bf16x8 a3 = __builtin_bit_cast(bf16x8, pm);
                    acc3[t][0] = __builtin_amdgcn_mfma_f32_16x16x32_bf16(a3, bfr0, acc3[t][0], 0, 0, 0);
                    acc3[t][1] = __builtin_amdgcn_mfma_f32_16x16x32_bf16(a3, bfr1, acc3[t][1], 0, 0, 0);
                }
            }
            float ps[2] = {0.f, 0.f};
            #pragma unroll
            for (int t = 0; t < 8; ++t) {
                const int v0 = t * 16 + q * 4;
                f32x4 iv = *reinterpret_cast<const f32x4*>(&s_inv[v0]);
                f32x4 wm = *reinterpret_cast<const f32x4*>(&s_wm[v0]);
                #pragma unroll
                for (int jj = 0; jj < 2; ++jj) {
                    const float bc = b2g[hf * 128 + (jj * 4 + wid) * 16 + l15];
                    f32x4 a = acc3[t][jj];
                    #pragma unroll
                    for (int r = 0; r < 4; ++r)
                        ps[jj] += fmaxf(fmaf(a[r], iv[r], bc), 0.f) * wm[r];
                }
            }
            #pragma unroll
            for (int jj = 0; jj < 2; ++jj) {
                ps[jj] += __shfl_xor(ps[jj], 16);
                ps[jj] += __shfl_xor(ps[jj], 32);
                if (q == 0)
                    sgf[hf * 128 + (jj * 4 + wid) * 16 + l15] = ps[jj];
            }
        }
        __syncthreads();   // half consumed before next half overwrites xabuf / sgf done
    }

    // ---------- heads inline: out = g @ {Wmu,Wlv} + bias (2 thr / output) ----------
    {
        float* sp = reinterpret_cast<float*>(rb + 1024);   // [2][128] partials
        const int oi = tid & 127, part = tid >> 7;
        const int which = oi >> 6, l = oi & 63;
        const float* W = which ? Wlv : Wmu;
        float acc = 0.f;
        const int c0 = part * 128;
        #pragma unroll 8
        for (int cc = 0; cc < 128; ++cc)
            acc = fmaf(sgf[c0 + cc], W[(c0 + cc) * L_ + l], acc);
        sp[part * 128 + oi] = acc;
        __syncthreads();
        if (tid < 128) {
            const int w2 = tid >> 6, l2 = tid & 63;
            float r = sp[tid] + sp[128 + tid];
            r += w2 ? blv[l2] : bmu[l2];
            out[(size_t)w2 * B_ * L_ + (size_t)b * L_ + l2] = r;
        }
    }
}

extern "C" void kernel_launch(void* const* d_in, const int* in_sizes, int n_in,
                              void* d_out, int out_size, void* d_ws, size_t ws_size,
                              hipStream_t stream) {
    const float* x   = (const float*)d_in[0];
    const float* adj = (const float*)d_in[1];
    const float* W1  = (const float*)d_in[2];
    const float* b1  = (const float*)d_in[3];
    const float* W2  = (const float*)d_in[4];
    const float* b2  = (const float*)d_in[5];
    const float* Wmu = (const float*)d_in[6];
    const float* bmu = (const float*)d_in[7];
    const float* Wlv = (const float*)d_in[8];
    const float* blv = (const float*)d_in[9];
    float* out = (float*)d_out;
    uint16_t* ws = (uint16_t*)d_ws;

    hipLaunchKernelGGL(prep_weights, dim3(48), dim3(256), 0, stream, W1, W2, ws);
    hipLaunchKernelGGL(fused_kernel, dim3(B_), dim3(256), 0, stream,
                       x, adj, ws, b1, b2, Wmu, bmu, Wlv, blv, out);
}

// Round 9
// 129.498 us; speedup vs baseline: 2.0324x; 1.2138x over previous
//
#include <hip/hip_runtime.h>
#include <hip/hip_bf16.h>
#include <stdint.h>

#define B_ 1024
#define N_ 128
#define D_ 128
#define H_ 256
#define L_ 64
#define INF_ 0x3FFFFFFF

typedef __attribute__((ext_vector_type(8))) short bf16x8;
typedef __attribute__((ext_vector_type(4))) float f32x4;
typedef __attribute__((ext_vector_type(4))) uint32_t u32x4;
typedef __attribute__((ext_vector_type(2))) uint32_t u32x2;

__device__ __forceinline__ uint32_t pack2(float a, float b) {
    __hip_bfloat162 h = __float22bfloat162_rn(make_float2(a, b));
    uint32_t u;
    __builtin_memcpy(&u, &h, 4);
    return u;
}

// ---------------- weight prep: fragment-linear bf16 layouts in ws ----------------
__global__ void prep_weights(const float* __restrict__ W1, const float* __restrict__ W2,
                             uint16_t* __restrict__ ws) {
    int t = blockIdx.x * 256 + threadIdx.x;
    if (t < 4096) {                       // W1T A-frags: A[m=h][k=f]
        int lane = t & 63, fkb = t >> 6;
        int tm = fkb >> 2, kb = fkb & 3;
        int h  = tm * 16 + (lane & 15);
        int k0 = kb * 32 + (lane >> 4) * 8;
        u32x4 w;
        #pragma unroll
        for (int p = 0; p < 4; ++p)
            w[p] = pack2(W1[(k0 + 2*p) * H_ + h], W1[(k0 + 2*p + 1) * H_ + h]);
        *reinterpret_cast<u32x4*>(&ws[t * 8]) = w;
    } else if (t < 12288) {               // W2 B-frags: B[k][n]
        int t2 = t - 4096;
        int lane = t2 & 63, g = t2 >> 6;
        int tn = g >> 3, kb = g & 7;
        int n  = tn * 16 + (lane & 15);
        int k0 = kb * 32 + (lane >> 4) * 8;
        u32x4 w;
        #pragma unroll
        for (int p = 0; p < 4; ++p)
            w[p] = pack2(W2[(k0 + 2*p) * H_ + n], W2[(k0 + 2*p + 1) * H_ + n]);
        *reinterpret_cast<u32x4*>(&ws[32768 + t2 * 8]) = w;
    }
}

// ---------------- fused kernel: 1 block per graph, 256 threads, 2 blocks/CU (no spill) ----------------
__global__ __launch_bounds__(256, 2) void fused_kernel(
    const float* __restrict__ x, const float* __restrict__ adj,
    const uint16_t* __restrict__ ws,
    const float* __restrict__ b1g, const float* __restrict__ b2g,
    const float* __restrict__ Wmu, const float* __restrict__ bmu,
    const float* __restrict__ Wlv, const float* __restrict__ blv,
    float* __restrict__ out)
{
    // xabuf 32 KB: BFS-state overlay -> xa frags -> M2 half-buffers
    // rb    16 KB: x f32 chunk (swizzled) -> h1 quarters -> s_g + head partials
    __shared__ __align__(16) uint16_t xabuf[16384];
    __shared__ __align__(16) uint8_t  rb[16384];
    __shared__ __align__(16) uint32_t tnbr[128][4];
    __shared__ float    s_inv[128];
    __shared__ float    s_wm[128];
    __shared__ uint32_t visw[4], actw[4], newlyw[4];
    __shared__ int      s_root;

    uint32_t* adjm     = reinterpret_cast<uint32_t*>(xabuf);        // [512]
    int*      s_order  = reinterpret_cast<int*>(xabuf) + 512;       // [128]
    int*      s_parent = reinterpret_cast<int*>(xabuf) + 640;       // [128]
    int*      s_key    = reinterpret_cast<int*>(xabuf) + 768;       // [128]

    const int tid  = threadIdx.x;
    const int b    = blockIdx.x;
    const int wid  = tid >> 6;          // 0..3
    const int lane = tid & 63;
    const int l15  = lane & 15;
    const int q    = lane >> 4;

    const float4* xg4 = reinterpret_cast<const float4*>(x + (size_t)b * N_ * D_);
    const float*  ag  = adj + (size_t)b * N_ * N_;

    // ---------- prefetch x chunk 0: 1024 float4 / 256 thr = 4 each ----------
    const int prow = tid >> 3;               // base row (i adds 32)
    const int pcol = tid & 7;
    const int pswz = pcol ^ (prow & 7);      // same swizzle for all i (32 ≡ 0 mod 8)
    float4 pf[4];
    #pragma unroll
    for (int i = 0; i < 4; ++i)
        pf[i] = xg4[(prow + i * 32) * 32 + pcol];

    // ---------- init + adj -> bitmasks (2 threads/row) ----------
    if (tid < 128) { s_order[tid] = INF_; s_parent[tid] = 0; }
    if (tid < 4)   { visw[tid] = 0u; actw[tid] = 0u; }
    if (tid == 0)  { s_root = 128; }
    {
        const int v = tid >> 1, hf = tid & 1;
        const float4* ag4 = reinterpret_cast<const float4*>(ag + v * N_ + hf * 64);
        uint32_t w0 = 0, w1 = 0;
        #pragma unroll
        for (int i = 0; i < 16; ++i) {
            float4 f = ag4[i];
            uint32_t bs = (f.x > 0.5f ? 1u : 0u) | (f.y > 0.5f ? 2u : 0u) |
                          (f.z > 0.5f ? 4u : 0u) | (f.w > 0.5f ? 8u : 0u);
            int base = i * 4;
            if (base < 32) w0 |= bs << base; else w1 |= bs << (base - 32);
        }
        adjm[v * 4 + hf * 2]     = w0;
        adjm[v * 4 + hf * 2 + 1] = w1;
    }
    __syncthreads();

    // ---------- active nodes + root ----------
    if (tid < 128) {
        uint32_t any = adjm[tid*4+0] | adjm[tid*4+1] | adjm[tid*4+2] | adjm[tid*4+3];
        if (any) {
            atomicMin(&s_root, tid);
            atomicOr(&actw[tid >> 5], 1u << (tid & 31));
        }
    }
    __syncthreads();
    int counter = 0;
    if (s_root < 128) {
        counter = 1;
        if (tid == 0) {
            s_order[s_root] = 0;
            visw[s_root >> 5] = 1u << (s_root & 31);
        }
    }
    __syncthreads();

    // ---------- level-synchronous FIFO BFS ----------
    for (int step = 0; step < N_ - 1; ++step) {
        if (tid < 4) newlyw[tid] = 0u;
        __syncthreads();
        int newly = 0, po = INF_, par = 0;
        if (tid < 128 && s_order[tid] >= INF_) {
            #pragma unroll
            for (int w = 0; w < 4; ++w) {
                uint32_t m = adjm[tid * 4 + w] & visw[w];
                while (m) {
                    int u = (w << 5) + __ffs(m) - 1; m &= m - 1;
                    int o = s_order[u];
                    if (o < po) { po = o; par = u; }
                }
            }
            newly = (po < INF_);
            if (newly) {
                s_key[tid] = po * N_ + tid;
                atomicOr(&newlyw[tid >> 5], 1u << (tid & 31));
            }
        }
        __syncthreads();
        int myk = newly ? po * N_ + tid : 0x7FFFFFFF;
        int cnt = 0, rank = 0;
        #pragma unroll
        for (int w = 0; w < 4; ++w) {
            uint32_t m = newlyw[w];
            cnt += __popc(m);
            while (m) {
                int u = (w << 5) + __ffs(m) - 1; m &= m - 1;
                rank += (s_key[u] < myk);
            }
        }
        if (newly) {
            s_order[tid]  = counter + rank;
            s_parent[tid] = par;
            atomicOr(&visw[tid >> 5], 1u << (tid & 31));
        }
        counter += cnt;
        __syncthreads();
        if (cnt == 0) break;
    }

    // ---------- tree masks + degrees + pool weights ----------
    if (tid < 128) { tnbr[tid][0] = 0; tnbr[tid][1] = 0; tnbr[tid][2] = 0; tnbr[tid][3] = 0; }
    __syncthreads();
    if (tid < 128 && s_order[tid] > 0 && s_order[tid] < INF_) {
        int p = s_parent[tid];
        atomicOr(&tnbr[tid][p >> 5], 1u << (p & 31));
        atomicOr(&tnbr[p][tid >> 5], 1u << (tid & 31));
    }
    __syncthreads();
    if (tid < 128) {
        int d = 1 + __popc(tnbr[tid][0]) + __popc(tnbr[tid][1]) +
                    __popc(tnbr[tid][2]) + __popc(tnbr[tid][3]);
        int num = __popc(actw[0]) + __popc(actw[1]) + __popc(actw[2]) + __popc(actw[3]);
        int act = (actw[tid >> 5] >> (tid & 31)) & 1;
        s_inv[tid] = 1.0f / (float)d;
        s_wm[tid]  = act ? (1.0f / (float)(num > 0 ? num : 1)) : 0.0f;
    }
    __syncthreads();   // BFS overlay in xabuf dead; agg1 may overwrite

    // ---------- agg1: 4 rounds {stage f32 chunk -> gather -> xa frags} ----------
    float4* rbF4 = reinterpret_cast<float4*>(rb);
    const int gv = tid >> 1, gp2 = tid & 1;     // row, 16-feat half

    for (int r = 0; r < 4; ++r) {
        #pragma unroll
        for (int i = 0; i < 4; ++i)
            rbF4[(prow + i * 32) * 8 + pswz] = pf[i];
        if (r < 3) {                             // prefetch next chunk early (T14)
            #pragma unroll
            for (int i = 0; i < 4; ++i)
                pf[i] = xg4[(prow + i * 32) * 32 + (r + 1) * 8 + pcol];
        }
        __syncthreads();
        float acc[16];
        #pragma unroll
        for (int k = 0; k < 4; ++k) {
            float4 a = rbF4[gv * 8 + ((gp2 * 4 + k) ^ (gv & 7))];
            acc[k*4+0] = a.x; acc[k*4+1] = a.y; acc[k*4+2] = a.z; acc[k*4+3] = a.w;
        }
        #pragma unroll
        for (int w = 0; w < 4; ++w) {
            uint32_t m = tnbr[gv][w];
            while (m) {
                int u = (w << 5) + __ffs(m) - 1; m &= m - 1;
                #pragma unroll
                for (int k = 0; k < 4; ++k) {
                    float4 n = rbF4[u * 8 + ((gp2 * 4 + k) ^ (u & 7))];
                    acc[k*4+0] += n.x; acc[k*4+1] += n.y;
                    acc[k*4+2] += n.z; acc[k*4+3] += n.w;
                }
            }
        }
        const float inv = s_inv[gv];
        #pragma unroll
        for (int gg = 0; gg < 2; ++gg) {
            const int gp = gp2 * 2 + gg;
            u32x4 wv;
            wv[0] = pack2(acc[gg*8+0] * inv, acc[gg*8+1] * inv);
            wv[1] = pack2(acc[gg*8+2] * inv, acc[gg*8+3] * inv);
            wv[2] = pack2(acc[gg*8+4] * inv, acc[gg*8+5] * inv);
            wv[3] = pack2(acc[gg*8+6] * inv, acc[gg*8+7] * inv);
            *reinterpret_cast<u32x4*>(
                &xabuf[(((gv >> 4) * 4 + r) * 64 + gp * 16 + (gv & 15)) * 8]) = wv;
        }
        __syncthreads();
    }

    // ---------- m1/m2 interleaved over 4 h-chunks (64 h each), acc2 persistent ----------
    // m2 n-tile ownership INTERLEAVED: acc2[t][j] <-> global tn = j*4+wid.
    uint16_t* h1 = reinterpret_cast<uint16_t*>(rb);
    const bf16x8* wsA = reinterpret_cast<const bf16x8*>(ws);
    const bf16x8* wsB = reinterpret_cast<const bf16x8*>(ws + 32768);

    f32x4 acc2[8][4];
    #pragma unroll
    for (int t = 0; t < 8; ++t)
        #pragma unroll
        for (int j = 0; j < 4; ++j) acc2[t][j] = (f32x4){0.f, 0.f, 0.f, 0.f};

    const int kbl_w = wid >> 1;                                 // 32-h half within chunk
    const int sl    = l15 + 16 * (((wid & 1) * 2 + (q >> 1)) & 3);

    for (int hc = 0; hc < 4; ++hc) {
        const int tm = hc * 4 + wid;                            // h-tile (m1 A index)
        const int m0 = tm * 16 + q * 4;
        // group 0 (node-tiles 0..3): compute -> barrier -> write
        f32x4 acc1[4];
        #pragma unroll
        for (int j = 0; j < 4; ++j) acc1[j] = (f32x4){0.f, 0.f, 0.f, 0.f};
        #pragma unroll
        for (int kb = 0; kb < 4; ++kb) {
            bf16x8 afr = wsA[(tm * 4 + kb) * 64 + lane];
            #pragma unroll
            for (int j = 0; j < 4; ++j) {
                bf16x8 bfr = *reinterpret_cast<const bf16x8*>(
                    &xabuf[((j * 4 + kb) * 64 + lane) * 8]);
                acc1[j] = __builtin_amdgcn_mfma_f32_16x16x32_bf16(
                    afr, bfr, acc1[j], 0, 0, 0);
            }
        }
        __syncthreads();   // prev m2 finished reading h1q
        {
            f32x4 bb = *reinterpret_cast<const f32x4*>(b1g + m0);
            #pragma unroll
            for (int j = 0; j < 4; ++j) {
                f32x4 v = acc1[j];
                float v0 = fmaxf(v[0] + bb[0], 0.f), v1 = fmaxf(v[1] + bb[1], 0.f);
                float v2 = fmaxf(v[2] + bb[2], 0.f), v3 = fmaxf(v[3] + bb[3], 0.f);
                u32x2 w; w[0] = pack2(v0, v1); w[1] = pack2(v2, v3);
                *reinterpret_cast<u32x2*>(
                    &h1[((j * 2 + kbl_w) * 64 + sl) * 8 + (q & 1) * 4]) = w;
            }
        }
        // group 1 (node-tiles 4..7): compute -> write
        #pragma unroll
        for (int j = 0; j < 4; ++j) acc1[j] = (f32x4){0.f, 0.f, 0.f, 0.f};
        #pragma unroll
        for (int kb = 0; kb < 4; ++kb) {
            bf16x8 afr = wsA[(tm * 4 + kb) * 64 + lane];
            #pragma unroll
            for (int j = 0; j < 4; ++j) {
                bf16x8 bfr = *reinterpret_cast<const bf16x8*>(
                    &xabuf[(((4 + j) * 4 + kb) * 64 + lane) * 8]);
                acc1[j] = __builtin_amdgcn_mfma_f32_16x16x32_bf16(
                    afr, bfr, acc1[j], 0, 0, 0);
            }
        }
        {
            f32x4 bb = *reinterpret_cast<const f32x4*>(b1g + m0);
            #pragma unroll
            for (int j = 0; j < 4; ++j) {
                f32x4 v = acc1[j];
                float v0 = fmaxf(v[0] + bb[0], 0.f), v1 = fmaxf(v[1] + bb[1], 0.f);
                float v2 = fmaxf(v[2] + bb[2], 0.f), v3 = fmaxf(v[3] + bb[3], 0.f);
                u32x2 w; w[0] = pack2(v0, v1); w[1] = pack2(v2, v3);
                *reinterpret_cast<u32x2*>(
                    &h1[(((4 + j) * 2 + kbl_w) * 64 + sl) * 8 + (q & 1) * 4]) = w;
            }
        }
        __syncthreads();   // h1q ready
        // m2: accumulate this chunk's k-range into persistent acc2 (tn = j*4+wid)
        #pragma unroll
        for (int kbl = 0; kbl < 2; ++kbl) {
            const int kb2 = hc * 2 + kbl;
            bf16x8 bfr0 = wsB[((0 * 4 + wid) * 8 + kb2) * 64 + lane];
            bf16x8 bfr1 = wsB[((1 * 4 + wid) * 8 + kb2) * 64 + lane];
            bf16x8 bfr2 = wsB[((2 * 4 + wid) * 8 + kb2) * 64 + lane];
            bf16x8 bfr3 = wsB[((3 * 4 + wid) * 8 + kb2) * 64 + lane];
            #pragma unroll
            for (int t = 0; t < 8; ++t) {
                bf16x8 a2 = *reinterpret_cast<const bf16x8*>(
                    &h1[((t * 2 + kbl) * 64 + lane) * 8]);
                acc2[t][0] = __builtin_amdgcn_mfma_f32_16x16x32_bf16(a2, bfr0, acc2[t][0], 0, 0, 0);
                acc2[t][1] = __builtin_amdgcn_mfma_f32_16x16x32_bf16(a2, bfr1, acc2[t][1], 0, 0, 0);
                acc2[t][2] = __builtin_amdgcn_mfma_f32_16x16x32_bf16(a2, bfr2, acc2[t][2], 0, 0, 0);
                acc2[t][3] = __builtin_amdgcn_mfma_f32_16x16x32_bf16(a2, bfr3, acc2[t][3], 0, 0, 0);
            }
        }
    }

    // ---------- agg2 in two h2-halves; ALL waves write + compute each half ----------
    float* sgf = reinterpret_cast<float*>(rb);            // s_g[256] (1 KB)
    #pragma unroll
    for (int hf = 0; hf < 2; ++hf) {
        // write this half's M2 frags: j = hf*2+jj, local tile tnl = jj*4+wid (0..7)
        #pragma unroll
        for (int t = 0; t < 8; ++t) {
            const int kbh = t >> 1;
            const int slw = l15 + 16 * ((2 * t + (q >> 1)) & 3);
            #pragma unroll
            for (int jj = 0; jj < 2; ++jj) {
                const int tnl = jj * 4 + wid;
                f32x4 v = acc2[t][hf * 2 + jj];
                u32x2 w; w[0] = pack2(v[0], v[1]); w[1] = pack2(v[2], v[3]);
                *reinterpret_cast<u32x2*>(
                    &xabuf[((tnl * 4 + kbh) * 64 + slw) * 8 + (q & 1) * 4]) = w;
            }
        }
        __syncthreads();   // M2 half ready (also fences h1 reads at hf=0)
        {
            f32x4 acc3[8][2];
            #pragma unroll
            for (int t = 0; t < 8; ++t) {
                acc3[t][0] = (f32x4){0.f, 0.f, 0.f, 0.f};
                acc3[t][1] = (f32x4){0.f, 0.f, 0.f, 0.f};
            }
            #pragma unroll
            for (int kb = 0; kb < 4; ++kb) {
                bf16x8 bfr0 = *reinterpret_cast<const bf16x8*>(
                    &xabuf[(((0 * 4 + wid) * 4 + kb) * 64 + lane) * 8]);
                bf16x8 bfr1 = *reinterpret_cast<const bf16x8*>(
                    &xabuf[(((1 * 4 + wid) * 4 + kb) * 64 + lane) * 8]);
                #pragma unroll
                for (int t = 0; t < 8; ++t) {
                    int v = t * 16 + l15;
                    uint32_t word = tnbr[v][kb];
                    uint32_t by = (word >> (q * 8)) & 0xFFu;
                    if ((v >> 3) == kb * 4 + q) by |= 1u << (v & 7);
                    u32x4 pm;
                    #pragma unroll
                    for (int pp = 0; pp < 4; ++pp)
                        pm[pp] = (((by >> (2 * pp)) & 1u) ? 0x3F80u : 0u) |
                                 (((by >> (2 * pp + 1)) & 1u) ? 0x3F800000u : 0u);
                    bf16x8 a3 = __builtin_bit_cast(bf16x8, pm);
                    acc3[t][0] = __builtin_amdgcn_mfma_f32_16x16x32_bf16(a3, bfr0, acc3[t][0], 0, 0, 0);
                    acc3[t][1] = __builtin_amdgcn_mfma_f32_16x16x32_bf16(a3, bfr1, acc3[t][1], 0, 0, 0);
                }
            }
            float ps[2] = {0.f, 0.f};
            #pragma unroll
            for (int t = 0; t < 8; ++t) {
                const int v0 = t * 16 + q * 4;
                f32x4 iv = *reinterpret_cast<const f32x4*>(&s_inv[v0]);
                f32x4 wm = *reinterpret_cast<const f32x4*>(&s_wm[v0]);
                #pragma unroll
                for (int jj = 0; jj < 2; ++jj) {
                    const float bc = b2g[hf * 128 + (jj * 4 + wid) * 16 + l15];
                    f32x4 a = acc3[t][jj];
                    #pragma unroll
                    for (int r = 0; r < 4; ++r)
                        ps[jj] += fmaxf(fmaf(a[r], iv[r], bc), 0.f) * wm[r];
                }
            }
            #pragma unroll
            for (int jj = 0; jj < 2; ++jj) {
                ps[jj] += __shfl_xor(ps[jj], 16);
                ps[jj] += __shfl_xor(ps[jj], 32);
                if (q == 0)
                    sgf[hf * 128 + (jj * 4 + wid) * 16 + l15] = ps[jj];
            }
        }
        __syncthreads();   // half consumed before next half overwrites xabuf / sgf done
    }

    // ---------- heads inline: out = g @ {Wmu,Wlv} + bias (2 thr / output) ----------
    {
        float* sp = reinterpret_cast<float*>(rb + 1024);   // [2][128] partials
        const int oi = tid & 127, part = tid >> 7;
        const int which = oi >> 6, l = oi & 63;
        const float* W = which ? Wlv : Wmu;
        float acc = 0.f;
        const int c0 = part * 128;
        #pragma unroll 8
        for (int cc = 0; cc < 128; ++cc)
            acc = fmaf(sgf[c0 + cc], W[(c0 + cc) * L_ + l], acc);
        sp[part * 128 + oi] = acc;
        __syncthreads();
        if (tid < 128) {
            const int w2 = tid >> 6, l2 = tid & 63;
            float r = sp[tid] + sp[128 + tid];
            r += w2 ? blv[l2] : bmu[l2];
            out[(size_t)w2 * B_ * L_ + (size_t)b * L_ + l2] = r;
        }
    }
}

extern "C" void kernel_launch(void* const* d_in, const int* in_sizes, int n_in,
                              void* d_out, int out_size, void* d_ws, size_t ws_size,
                              hipStream_t stream) {
    const float* x   = (const float*)d_in[0];
    const float* adj = (const float*)d_in[1];
    const float* W1  = (const float*)d_in[2];
    const float* b1  = (const float*)d_in[3];
    const float* W2  = (const float*)d_in[4];
    const float* b2  = (const float*)d_in[5];
    const float* Wmu = (const float*)d_in[6];
    const float* bmu = (const float*)d_in[7];
    const float* Wlv = (const float*)d_in[8];
    const float* blv = (const float*)d_in[9];
    float* out = (float*)d_out;
    uint16_t* ws = (uint16_t*)d_ws;

    hipLaunchKernelGGL(prep_weights, dim3(48), dim3(256), 0, stream, W1, W2, ws);
    hipLaunchKernelGGL(fused_kernel, dim3(B_), dim3(256), 0, stream,
                       x, adj, ws, b1, b2, Wmu, bmu, Wlv, blv, out);
}